// Round 1
// baseline (310.716 us; speedup 1.0000x reference)
//
#include <hip/hip_runtime.h>
#include <math.h>

#define B_ 8
#define C_ 64
#define N_ 4096
#define O_ 64
#define SCALE_ 0.3779644730092272f  // 1/sqrt(7)

typedef __bf16 bf16x8 __attribute__((ext_vector_type(8)));
typedef float f32x4 __attribute__((ext_vector_type(4)));
typedef unsigned short ushortx8 __attribute__((ext_vector_type(8)));

__device__ __forceinline__ unsigned short f2bf(float f) {
  union { float f; unsigned u; } v; v.f = f;
  unsigned r = v.u + 0x7FFFu + ((v.u >> 16) & 1u);  // round-to-nearest-even
  return (unsigned short)(r >> 16);
}
__device__ __forceinline__ float bf2f(unsigned short h) {
  union { unsigned u; float f; } v; v.u = ((unsigned)h) << 16;
  return v.f;
}

// ---------------------------------------------------------------------------
// Kernel 1: per-pixel projections. x:[B][C][N] f32 -> Qh/Ql/Kh/Kl:[b][n][64]
// bf16 hi/lo split (Q pre-scaled by SCALE), V:[b][o][n] bf16.
// ---------------------------------------------------------------------------
__global__ __launch_bounds__(128)
void proj_kernel(const float* __restrict__ x,
                 const float* __restrict__ Wq, const float* __restrict__ bq,
                 const float* __restrict__ Wk, const float* __restrict__ bk,
                 const float* __restrict__ Wv, const float* __restrict__ bv,
                 unsigned short* __restrict__ Qh, unsigned short* __restrict__ Ql,
                 unsigned short* __restrict__ Kh, unsigned short* __restrict__ Kl,
                 unsigned short* __restrict__ Vt)
{
  const int b = blockIdx.x >> 5;
  const int n = ((blockIdx.x & 31) << 7) + threadIdx.x;

  const float* xb = x + (size_t)b * C_ * N_ + n;
  float xr[C_];
  #pragma unroll
  for (int c = 0; c < C_; ++c) xr[c] = xb[(size_t)c * N_];

  const size_t qrow = ((size_t)b * N_ + n) * (size_t)O_;

  #pragma unroll 1
  for (int o = 0; o < O_; ++o) {
    const float4* wq = (const float4*)(Wq + (o << 6));
    const float4* wk = (const float4*)(Wk + (o << 6));
    const float4* wv = (const float4*)(Wv + (o << 6));
    float qa = bq[o], ka = bk[o], va = bv[o];
    #pragma unroll
    for (int c4 = 0; c4 < 16; ++c4) {
      float4 a = wq[c4], kk = wk[c4], vv = wv[c4];
      float x0 = xr[4*c4+0], x1 = xr[4*c4+1], x2 = xr[4*c4+2], x3 = xr[4*c4+3];
      qa += a.x*x0 + a.y*x1 + a.z*x2 + a.w*x3;
      ka += kk.x*x0 + kk.y*x1 + kk.z*x2 + kk.w*x3;
      va += vv.x*x0 + vv.y*x1 + vv.z*x2 + vv.w*x3;
    }
    qa *= SCALE_;
    unsigned short qh = f2bf(qa);
    unsigned short ql = f2bf(qa - bf2f(qh));
    unsigned short kh = f2bf(ka);
    unsigned short kl = f2bf(ka - bf2f(kh));
    Qh[qrow + o] = qh;
    Ql[qrow + o] = ql;
    Kh[qrow + o] = kh;
    Kl[qrow + o] = kl;
    Vt[((size_t)b * O_ + o) * (size_t)N_ + n] = f2bf(va);
  }
}

// ---------------------------------------------------------------------------
// Kernel 2: flash attention. Block = (b, 64 q-rows), 4 waves x 16 rows.
// K/V chunks of 64 staged in LDS (row pad +8 -> free 2-way bank aliasing).
// S via 3-term bf16 split (f32-accurate logits), online softmax, PV bf16.
// Writes out[b][n][o] f32 = d_out layout directly.
// ---------------------------------------------------------------------------
__global__ __launch_bounds__(256)
void flash_kernel(const unsigned short* __restrict__ Qh, const unsigned short* __restrict__ Ql,
                  const unsigned short* __restrict__ Kh, const unsigned short* __restrict__ Kl,
                  const unsigned short* __restrict__ Vt, float* __restrict__ out)
{
  __shared__ __align__(16) unsigned short KhL[64][72];
  __shared__ __align__(16) unsigned short KlL[64][72];
  __shared__ __align__(16) unsigned short VtL[64][72];
  __shared__ __align__(16) unsigned short PL[4][16][72];

  const int tid  = threadIdx.x;
  const int w    = tid >> 6;
  const int lane = tid & 63;
  const int lr   = lane & 15;   // A-row / B-col / D-col
  const int lq   = lane >> 4;   // quad
  const int koff = lq << 3;     // k-elem offset within 32-chunk

  const int b  = blockIdx.x >> 6;
  const int q0 = (blockIdx.x & 63) << 6;
  const int qw = q0 + (w << 4);

  // Q fragments (A layout: row=lane&15, k=(lane>>4)*8+j), hoisted once
  bf16x8 qh[2], ql[2];
  {
    const unsigned short* qp = Qh + ((size_t)b * N_ + qw + lr) * (size_t)O_;
    const unsigned short* lp = Ql + ((size_t)b * N_ + qw + lr) * (size_t)O_;
    #pragma unroll
    for (int cc = 0; cc < 2; ++cc) {
      qh[cc] = *(const bf16x8*)(qp + cc * 32 + koff);
      ql[cc] = *(const bf16x8*)(lp + cc * 32 + koff);
    }
  }

  f32x4 acc[4];
  float m_run[4], l_run[4];
  #pragma unroll
  for (int t = 0; t < 4; ++t) acc[t] = (f32x4){0.f, 0.f, 0.f, 0.f};
  #pragma unroll
  for (int r = 0; r < 4; ++r) { m_run[r] = -INFINITY; l_run[r] = 0.f; }

  const unsigned short* KhB = Kh + (size_t)b * N_ * O_;
  const unsigned short* KlB = Kl + (size_t)b * N_ * O_;
  const unsigned short* VtB = Vt + (size_t)b * O_ * N_;

  for (int kc0 = 0; kc0 < N_; kc0 += 64) {
    // ---- stage K (hi/lo, [kc][c]) and V^T ([o][m]) chunks into LDS ----
    for (int idx = tid; idx < 512; idx += 256) {
      const int r  = idx >> 3;
      const int c8 = (idx & 7) << 3;
      *(ushortx8*)&KhL[r][c8] = *(const ushortx8*)(KhB + (size_t)(kc0 + r) * O_ + c8);
      *(ushortx8*)&KlL[r][c8] = *(const ushortx8*)(KlB + (size_t)(kc0 + r) * O_ + c8);
      *(ushortx8*)&VtL[r][c8] = *(const ushortx8*)(VtB + (size_t)r * N_ + kc0 + c8);
    }
    __syncthreads();

    // ---- S = Q K^T (3-term split), 4 subtiles of 16 cols ----
    f32x4 s[4];
    #pragma unroll
    for (int t = 0; t < 4; ++t) {
      const int row = (t << 4) + lr;
      bf16x8 kh0 = *(const bf16x8*)&KhL[row][koff];
      bf16x8 kh1 = *(const bf16x8*)&KhL[row][32 + koff];
      bf16x8 kl0 = *(const bf16x8*)&KlL[row][koff];
      bf16x8 kl1 = *(const bf16x8*)&KlL[row][32 + koff];
      f32x4 a = (f32x4){0.f, 0.f, 0.f, 0.f};
      a = __builtin_amdgcn_mfma_f32_16x16x32_bf16(qh[0], kh0, a, 0, 0, 0);
      a = __builtin_amdgcn_mfma_f32_16x16x32_bf16(qh[1], kh1, a, 0, 0, 0);
      a = __builtin_amdgcn_mfma_f32_16x16x32_bf16(qh[0], kl0, a, 0, 0, 0);
      a = __builtin_amdgcn_mfma_f32_16x16x32_bf16(qh[1], kl1, a, 0, 0, 0);
      a = __builtin_amdgcn_mfma_f32_16x16x32_bf16(ql[0], kh0, a, 0, 0, 0);
      a = __builtin_amdgcn_mfma_f32_16x16x32_bf16(ql[1], kh1, a, 0, 0, 0);
      s[t] = a;
    }

    // ---- online softmax (rows = lq*4+r, 16-lane butterfly over cols) ----
    #pragma unroll
    for (int r = 0; r < 4; ++r) {
      float mx = fmaxf(fmaxf(s[0][r], s[1][r]), fmaxf(s[2][r], s[3][r]));
      mx = fmaxf(mx, __shfl_xor(mx, 1));
      mx = fmaxf(mx, __shfl_xor(mx, 2));
      mx = fmaxf(mx, __shfl_xor(mx, 4));
      mx = fmaxf(mx, __shfl_xor(mx, 8));
      const float mnew = fmaxf(m_run[r], mx);
      const float corr = __expf(m_run[r] - mnew);
      float rs = 0.f;
      #pragma unroll
      for (int t = 0; t < 4; ++t) {
        float p = __expf(s[t][r] - mnew);
        s[t][r] = p;
        rs += p;
      }
      rs += __shfl_xor(rs, 1);
      rs += __shfl_xor(rs, 2);
      rs += __shfl_xor(rs, 4);
      rs += __shfl_xor(rs, 8);
      l_run[r] = l_run[r] * corr + rs;
      m_run[r] = mnew;
      #pragma unroll
      for (int t = 0; t < 4; ++t) acc[t][r] *= corr;
    }

    // ---- P (acc layout) -> LDS -> A-fragment layout ----
    #pragma unroll
    for (int t = 0; t < 4; ++t) {
      #pragma unroll
      for (int r = 0; r < 4; ++r) {
        PL[w][(lq << 2) + r][(t << 4) + lr] = f2bf(s[t][r]);
      }
    }
    __syncthreads();

    // ---- O += P V ----
    #pragma unroll
    for (int mc = 0; mc < 2; ++mc) {
      bf16x8 pf = *(const bf16x8*)&PL[w][lr][(mc << 5) + koff];
      #pragma unroll
      for (int t = 0; t < 4; ++t) {
        bf16x8 vf = *(const bf16x8*)&VtL[(t << 4) + lr][(mc << 5) + koff];
        acc[t] = __builtin_amdgcn_mfma_f32_16x16x32_bf16(pf, vf, acc[t], 0, 0, 0);
      }
    }
    __syncthreads();
  }

  // ---- epilogue: out[b][n][o] f32 ----
  #pragma unroll
  for (int t = 0; t < 4; ++t) {
    #pragma unroll
    for (int r = 0; r < 4; ++r) {
      const int grow = qw + (lq << 2) + r;
      out[((size_t)b * N_ + grow) * (size_t)O_ + (t << 4) + lr] = acc[t][r] / l_run[r];
    }
  }
}

extern "C" void kernel_launch(void* const* d_in, const int* in_sizes, int n_in,
                              void* d_out, int out_size, void* d_ws, size_t ws_size,
                              hipStream_t stream) {
  (void)in_sizes; (void)n_in; (void)out_size; (void)ws_size;
  const float* x  = (const float*)d_in[0];
  const float* Wq = (const float*)d_in[1];
  const float* bq = (const float*)d_in[2];
  const float* Wk = (const float*)d_in[3];
  const float* bk = (const float*)d_in[4];
  const float* Wv = (const float*)d_in[5];
  const float* bv = (const float*)d_in[6];
  float* out = (float*)d_out;

  const size_t SZ = (size_t)B_ * N_ * O_;  // 2,097,152 elems per buffer
  unsigned short* Qh = (unsigned short*)d_ws;
  unsigned short* Ql = Qh + SZ;
  unsigned short* Kh = Ql + SZ;
  unsigned short* Kl = Kh + SZ;
  unsigned short* Vt = Kl + SZ;

  proj_kernel<<<dim3(B_ * 32), dim3(128), 0, stream>>>(x, Wq, bq, Wk, bk, Wv, bv,
                                                       Qh, Ql, Kh, Kl, Vt);
  flash_kernel<<<dim3(B_ * (N_ / 64)), dim3(256), 0, stream>>>(Qh, Ql, Kh, Kl, Vt, out);
}

// Round 2
// 291.518 us; speedup vs baseline: 1.0659x; 1.0659x over previous
//
#include <hip/hip_runtime.h>
#include <math.h>

#define B_ 8
#define N_ 4096
#define SCALE_ 0.3779644730092272f  // 1/sqrt(7)

typedef __bf16 bf16x8 __attribute__((ext_vector_type(8)));
typedef float f32x4 __attribute__((ext_vector_type(4)));
typedef unsigned short ushortx8 __attribute__((ext_vector_type(8)));
typedef unsigned short ushort;
typedef unsigned int uint;

static __device__ __forceinline__ ushort f2bf(float f) {
  union { float f; unsigned u; } v; v.f = f;
  unsigned r = v.u + 0x7FFFu + ((v.u >> 16) & 1u);  // RNE
  return (ushort)(r >> 16);
}
static __device__ __forceinline__ float bf2f(ushort h) {
  union { unsigned u; float f; } v; v.u = ((unsigned)h) << 16;
  return v.f;
}

// ---------------------------------------------------------------------------
// Kernel 1: projections. x:[B][64][N] f32 -> Qh/Ql/Kh/Kl:[b][n][64] bf16
// hi/lo split (Q pre-scaled), V^T:[b][o][n] bf16.
// Row results accumulated in registers, stored as b128 chunks (the R1 version
// did 2-byte stores at stride-64: ~8M L2 write txns -> ~110us; this fixes it).
// ---------------------------------------------------------------------------
__global__ __launch_bounds__(128)
void proj_kernel(const float* __restrict__ x,
                 const float* __restrict__ Wq, const float* __restrict__ bq,
                 const float* __restrict__ Wk, const float* __restrict__ bk,
                 const float* __restrict__ Wv, const float* __restrict__ bv,
                 ushort* __restrict__ Qh, ushort* __restrict__ Ql,
                 ushort* __restrict__ Kh, ushort* __restrict__ Kl,
                 ushort* __restrict__ Vt)
{
  const int b = blockIdx.x >> 5;
  const int n = ((blockIdx.x & 31) << 7) + threadIdx.x;

  const float* xb = x + ((size_t)b << 18) + n;
  float xr[64];
  #pragma unroll
  for (int c = 0; c < 64; ++c) xr[c] = xb[(size_t)c << 12];

  const size_t qrow = (((size_t)b << 12) + (size_t)n) << 6;
  ushort* vtb = Vt + ((size_t)b << 18) + n;

  #pragma unroll 1
  for (int oc = 0; oc < 4; ++oc) {
    uint qhp[8], qlp[8], khp[8], klp[8];
    #pragma unroll
    for (int j = 0; j < 16; ++j) {
      const int o = (oc << 4) + j;
      const float4* wq = (const float4*)(Wq + (o << 6));
      const float4* wk = (const float4*)(Wk + (o << 6));
      const float4* wv = (const float4*)(Wv + (o << 6));
      float qa = bq[o], ka = bk[o], va = bv[o];
      #pragma unroll
      for (int c4 = 0; c4 < 16; ++c4) {
        float4 a = wq[c4], kk = wk[c4], vv = wv[c4];
        float x0 = xr[4*c4+0], x1 = xr[4*c4+1], x2 = xr[4*c4+2], x3 = xr[4*c4+3];
        qa += a.x*x0 + a.y*x1 + a.z*x2 + a.w*x3;
        ka += kk.x*x0 + kk.y*x1 + kk.z*x2 + kk.w*x3;
        va += vv.x*x0 + vv.y*x1 + vv.z*x2 + vv.w*x3;
      }
      qa *= SCALE_;
      ushort qhs = f2bf(qa); ushort qls = f2bf(qa - bf2f(qhs));
      ushort khs = f2bf(ka); ushort kls = f2bf(ka - bf2f(khs));
      if (j & 1) {
        qhp[j >> 1] |= (uint)qhs << 16; qlp[j >> 1] |= (uint)qls << 16;
        khp[j >> 1] |= (uint)khs << 16; klp[j >> 1] |= (uint)kls << 16;
      } else {
        qhp[j >> 1] = qhs; qlp[j >> 1] = qls;
        khp[j >> 1] = khs; klp[j >> 1] = kls;
      }
      vtb[(size_t)o << 12] = f2bf(va);  // contiguous over lanes (n) -> coalesced
    }
    const size_t co = qrow + (oc << 4);
    *(ushortx8*)(Qh + co)     = *(ushortx8*)&qhp[0];
    *(ushortx8*)(Qh + co + 8) = *(ushortx8*)&qhp[4];
    *(ushortx8*)(Ql + co)     = *(ushortx8*)&qlp[0];
    *(ushortx8*)(Ql + co + 8) = *(ushortx8*)&qlp[4];
    *(ushortx8*)(Kh + co)     = *(ushortx8*)&khp[0];
    *(ushortx8*)(Kh + co + 8) = *(ushortx8*)&khp[4];
    *(ushortx8*)(Kl + co)     = *(ushortx8*)&klp[0];
    *(ushortx8*)(Kl + co + 8) = *(ushortx8*)&klp[4];
  }
}

// ---------------------------------------------------------------------------
// Kernel 2: flash attention, swapped-operand form.
// S^T = mfma(K-frag, Q-frag): lane holds S[q=lane&15][kv=16t+4*lq+r]
//   -> softmax fully per-lane (+2 shfl_xor for the 4-group reduce).
// O^T = mfma(V^T-frag, P^T-frag): P^T B-frag built in-register via 16 bpermute
//   + 8 selects (no P LDS round-trip, no second barrier).
// Double-buffered LDS, 1 barrier/iter, async-stage (loads issued post-barrier,
// ds_write at iter end). XCD-swizzled blockIdx: each XCD owns one batch.
// ---------------------------------------------------------------------------
__global__ __launch_bounds__(256)
void flash_kernel(const ushort* __restrict__ Qh, const ushort* __restrict__ Ql,
                  const ushort* __restrict__ Kh, const ushort* __restrict__ Kl,
                  const ushort* __restrict__ Vt, float* __restrict__ out)
{
  __shared__ __align__(16) ushort KhL[2][64][72];
  __shared__ __align__(16) ushort KlL[2][64][72];
  __shared__ __align__(16) ushort VtL[2][64][72];

  const int tid  = threadIdx.x;
  const int lane = tid & 63;
  const int w    = tid >> 6;
  const int lr   = lane & 15;
  const int lq   = lane >> 4;
  const int koff = lq << 3;

  // bijective XCD swizzle: 512 blocks = 8 XCDs x 64 -> XCD x gets batch x
  const int bidx = (blockIdx.x & 7) * 64 + (blockIdx.x >> 3);
  const int b  = bidx >> 6;
  const int qw = ((bidx & 63) << 6) + (w << 4);

  const ushort* KhB = Kh + ((size_t)b << 18);
  const ushort* KlB = Kl + ((size_t)b << 18);
  const ushort* VtB = Vt + ((size_t)b << 18);

  // Q fragments (B-frag: col=lane&15 -> q-row, k=koff+j), hoisted
  bf16x8 qh[2], ql[2];
  {
    const ushort* qp = Qh + ((((size_t)b << 12) + qw + lr) << 6);
    const ushort* lp = Ql + ((((size_t)b << 12) + qw + lr) << 6);
    qh[0] = *(const bf16x8*)(qp + koff);
    qh[1] = *(const bf16x8*)(qp + 32 + koff);
    ql[0] = *(const bf16x8*)(lp + koff);
    ql[1] = *(const bf16x8*)(lp + 32 + koff);
  }

  // staging slots: thread covers slots tid and tid+256 of 512 (row, colgroup)
  const int s0r = tid >> 3, sg = (tid & 7) << 3;
  const int s1r = s0r + 32;

  ushortx8 rkh0, rkh1, rkl0, rkl1, rv0, rv1;
  #define STAGE_LOAD(c0) do { \
    rkh0 = *(const ushortx8*)(KhB + (((size_t)((c0) + s0r)) << 6) + sg); \
    rkh1 = *(const ushortx8*)(KhB + (((size_t)((c0) + s1r)) << 6) + sg); \
    rkl0 = *(const ushortx8*)(KlB + (((size_t)((c0) + s0r)) << 6) + sg); \
    rkl1 = *(const ushortx8*)(KlB + (((size_t)((c0) + s1r)) << 6) + sg); \
    rv0  = *(const ushortx8*)(VtB + ((size_t)s0r << 12) + (c0) + sg); \
    rv1  = *(const ushortx8*)(VtB + ((size_t)s1r << 12) + (c0) + sg); \
  } while (0)
  #define STAGE_WRITE(bf) do { \
    *(ushortx8*)&KhL[bf][s0r][sg] = rkh0; \
    *(ushortx8*)&KhL[bf][s1r][sg] = rkh1; \
    *(ushortx8*)&KlL[bf][s0r][sg] = rkl0; \
    *(ushortx8*)&KlL[bf][s1r][sg] = rkl1; \
    *(ushortx8*)&VtL[bf][s0r][sg] = rv0; \
    *(ushortx8*)&VtL[bf][s1r][sg] = rv1; \
  } while (0)

  STAGE_LOAD(0);
  STAGE_WRITE(0);

  f32x4 acc[4];  // acc[t][r]: O^T[o=16t+4lq+r][q=lr]
  #pragma unroll
  for (int t = 0; t < 4; ++t) acc[t] = (f32x4){0.f, 0.f, 0.f, 0.f};
  float m_run = -INFINITY, l_run = 0.f;
  int cur = 0;

  const int src0 = lr + ((lane & 16) << 1);  // lr + 16*(2*(lq&1))
  const int src1 = src0 + 16;
  const bool hi2 = (lq & 2) != 0;

  for (int kc = 0; kc < 64; ++kc) {
    __syncthreads();
    STAGE_LOAD(((kc + 1) & 63) << 6);  // overlap with this iter's compute

    // ---- S^T = K * Q^T (3-term bf16 split) ----
    f32x4 s[4];
    #pragma unroll
    for (int t = 0; t < 4; ++t) {
      const int row = (t << 4) + lr;
      bf16x8 kh0 = *(const bf16x8*)&KhL[cur][row][koff];
      bf16x8 kh1 = *(const bf16x8*)&KhL[cur][row][32 + koff];
      bf16x8 kl0 = *(const bf16x8*)&KlL[cur][row][koff];
      bf16x8 kl1 = *(const bf16x8*)&KlL[cur][row][32 + koff];
      f32x4 a = (f32x4){0.f, 0.f, 0.f, 0.f};
      a = __builtin_amdgcn_mfma_f32_16x16x32_bf16(kh0, qh[0], a, 0, 0, 0);
      a = __builtin_amdgcn_mfma_f32_16x16x32_bf16(kh1, qh[1], a, 0, 0, 0);
      a = __builtin_amdgcn_mfma_f32_16x16x32_bf16(kl0, qh[0], a, 0, 0, 0);
      a = __builtin_amdgcn_mfma_f32_16x16x32_bf16(kl1, qh[1], a, 0, 0, 0);
      a = __builtin_amdgcn_mfma_f32_16x16x32_bf16(kh0, ql[0], a, 0, 0, 0);
      a = __builtin_amdgcn_mfma_f32_16x16x32_bf16(kh1, ql[1], a, 0, 0, 0);
      s[t] = a;
    }

    // ---- per-lane online softmax (all 16 values share q-row lr) ----
    float mx = s[0][0];
    #pragma unroll
    for (int t = 0; t < 4; ++t)
      #pragma unroll
      for (int r = 0; r < 4; ++r) mx = fmaxf(mx, s[t][r]);
    mx = fmaxf(mx, __shfl_xor(mx, 16));
    mx = fmaxf(mx, __shfl_xor(mx, 32));
    const float mnew = fmaxf(m_run, mx);
    const float corr = __expf(m_run - mnew);
    float rs = 0.f;
    #pragma unroll
    for (int t = 0; t < 4; ++t) {
      #pragma unroll
      for (int r = 0; r < 4; ++r) {
        float p = __expf(s[t][r] - mnew);
        s[t][r] = p;
        rs += p;
      }
    }
    rs += __shfl_xor(rs, 16);
    rs += __shfl_xor(rs, 32);
    l_run = l_run * corr + rs;
    m_run = mnew;
    #pragma unroll
    for (int t = 0; t < 4; ++t) acc[t] *= corr;

    // ---- pack P -> bf16 pairs ----
    uint P32[4][2];
    #pragma unroll
    for (int t = 0; t < 4; ++t) {
      P32[t][0] = (uint)f2bf(s[t][0]) | ((uint)f2bf(s[t][1]) << 16);
      P32[t][1] = (uint)f2bf(s[t][2]) | ((uint)f2bf(s[t][3]) << 16);
    }

    // ---- exchange to P^T B-frag + PV ----
    #pragma unroll
    for (int mc = 0; mc < 2; ++mc) {
      const int t0 = mc << 1, t1 = t0 + 1;
      uint a00 = (uint)__shfl((int)P32[t0][0], src0);
      uint a10 = (uint)__shfl((int)P32[t1][0], src0);
      uint a01 = (uint)__shfl((int)P32[t0][1], src0);
      uint a11 = (uint)__shfl((int)P32[t1][1], src0);
      uint a02 = (uint)__shfl((int)P32[t0][0], src1);
      uint a12 = (uint)__shfl((int)P32[t1][0], src1);
      uint a03 = (uint)__shfl((int)P32[t0][1], src1);
      uint a13 = (uint)__shfl((int)P32[t1][1], src1);
      union { uint u[4]; bf16x8 v; } pa;
      pa.u[0] = hi2 ? a10 : a00;  // j=0,1
      pa.u[1] = hi2 ? a11 : a01;  // j=2,3
      pa.u[2] = hi2 ? a12 : a02;  // j=4,5
      pa.u[3] = hi2 ? a13 : a03;  // j=6,7
      #pragma unroll
      for (int t = 0; t < 4; ++t) {
        bf16x8 vf = *(const bf16x8*)&VtL[cur][(t << 4) + lr][(mc << 5) + koff];
        acc[t] = __builtin_amdgcn_mfma_f32_16x16x32_bf16(vf, pa.v, acc[t], 0, 0, 0);
      }
    }

    STAGE_WRITE(cur ^ 1);  // vmcnt wait lands here, after compute
    cur ^= 1;
  }

  // ---- epilogue: out[b][q][o], lane's q-row = lr ----
  const float inv_l = 1.0f / l_run;
  const size_t rowb = ((((size_t)b << 12) + qw + lr) << 6);
  #pragma unroll
  for (int t = 0; t < 4; ++t) {
    f32x4 o4 = acc[t] * inv_l;
    *(f32x4*)(out + rowb + (t << 4) + (lq << 2)) = o4;
  }
  #undef STAGE_LOAD
  #undef STAGE_WRITE
}

extern "C" void kernel_launch(void* const* d_in, const int* in_sizes, int n_in,
                              void* d_out, int out_size, void* d_ws, size_t ws_size,
                              hipStream_t stream) {
  (void)in_sizes; (void)n_in; (void)out_size; (void)ws_size;
  const float* x  = (const float*)d_in[0];
  const float* Wq = (const float*)d_in[1];
  const float* bq = (const float*)d_in[2];
  const float* Wk = (const float*)d_in[3];
  const float* bk = (const float*)d_in[4];
  const float* Wv = (const float*)d_in[5];
  const float* bv = (const float*)d_in[6];
  float* out = (float*)d_out;

  const size_t SZ = (size_t)B_ * N_ * 64;
  ushort* Qh = (ushort*)d_ws;
  ushort* Ql = Qh + SZ;
  ushort* Kh = Ql + SZ;
  ushort* Kl = Kh + SZ;
  ushort* Vt = Kl + SZ;

  proj_kernel<<<dim3(B_ * 32), dim3(128), 0, stream>>>(x, Wq, bq, Wk, bk, Wv, bv,
                                                       Qh, Ql, Kh, Kl, Vt);
  flash_kernel<<<dim3(B_ * (N_ / 64)), dim3(256), 0, stream>>>(Qh, Ql, Kh, Kl, Vt, out);
}

// Round 3
// 140.587 us; speedup vs baseline: 2.2101x; 2.0736x over previous
//
#include <hip/hip_runtime.h>
#include <math.h>

#define B_ 8
#define N_ 4096
#define SCALE_ 0.3779644730092272f  // 1/sqrt(7)

typedef __bf16 bf16x8 __attribute__((ext_vector_type(8)));
typedef float f32x4 __attribute__((ext_vector_type(4)));
typedef unsigned short ushortx8 __attribute__((ext_vector_type(8)));
typedef unsigned short ushort;
typedef unsigned int uint;

static __device__ __forceinline__ ushort f2bf(float f) {
  union { float f; unsigned u; } v; v.f = f;
  unsigned r = v.u + 0x7FFFu + ((v.u >> 16) & 1u);  // RNE
  return (ushort)(r >> 16);
}
static __device__ __forceinline__ float bf2f(ushort h) {
  union { unsigned u; float f; } v; v.u = ((unsigned)h) << 16;
  return v.f;
}

// ---------------------------------------------------------------------------
// Kernel 1: projections, o-split for occupancy.
// Grid (128, 12): x-blocks = 256-pixel tiles, y = {Q,K,V} x {4 chunks of 16 o}.
// 1 thread/pixel computes 16 outputs; weights are block-uniform (scalar loads).
// R2 failure was 0.5 waves/SIMD (VALUBusy 9%) + scattered 2B V^T stores; this
// gives ~6 waves/SIMD and V^T goes through an LDS transpose -> 16B row stores.
// ---------------------------------------------------------------------------
__global__ __launch_bounds__(256)
void proj_kernel(const float* __restrict__ x,
                 const float* __restrict__ Wq, const float* __restrict__ bq,
                 const float* __restrict__ Wk, const float* __restrict__ bk,
                 const float* __restrict__ Wv, const float* __restrict__ bv,
                 ushort* __restrict__ Qh, ushort* __restrict__ Ql,
                 ushort* __restrict__ Kh, ushort* __restrict__ Kl,
                 ushort* __restrict__ Vt)
{
  __shared__ ushort sm[256][17];

  const int tid = threadIdx.x;
  const int gp  = (blockIdx.x << 8) + tid;   // global pixel
  const int b   = gp >> 12;
  const int n   = gp & 4095;
  const int y   = blockIdx.y;                // 0..11
  const int mat = y >> 2;                    // 0=Q 1=K 2=V
  const int o0  = (y & 3) << 4;

  const float* xb = x + ((size_t)b << 18) + n;
  float xr[64];
  #pragma unroll
  for (int c = 0; c < 64; ++c) xr[c] = xb[(size_t)c << 12];

  const float* W    = (mat == 0) ? Wq : (mat == 1) ? Wk : Wv;
  const float* bias = (mat == 0) ? bq : (mat == 1) ? bk : bv;

  float acc[16];
  #pragma unroll 1
  for (int j = 0; j < 16; ++j) {
    const float4* wr = (const float4*)(W + ((o0 + j) << 6));
    float a = bias[o0 + j];
    #pragma unroll
    for (int c4 = 0; c4 < 16; ++c4) {
      float4 w4 = wr[c4];
      a += w4.x * xr[4*c4] + w4.y * xr[4*c4+1] + w4.z * xr[4*c4+2] + w4.w * xr[4*c4+3];
    }
    acc[j] = a;
  }

  if (mat == 2) {
    // V: bf16 + 256x16 LDS transpose -> coalesced Vt[b][o][n] row stores
    #pragma unroll
    for (int j = 0; j < 16; ++j) sm[tid][j] = f2bf(acc[j]);
    __syncthreads();
    const int ol = tid >> 4;            // local o (0..15)
    const int p0 = (tid & 15) << 4;     // pixel group (16 pixels)
    uint pk[8];
    #pragma unroll
    for (int i = 0; i < 16; ++i) {
      ushort v = sm[p0 + i][ol];
      if (i & 1) pk[i >> 1] |= (uint)v << 16; else pk[i >> 1] = v;
    }
    const int nb = (blockIdx.x << 8) & 4095;
    ushort* dst = Vt + ((((size_t)b << 6) + o0 + ol) << 12) + nb + p0;
    *(ushortx8*)dst       = *(ushortx8*)&pk[0];
    *(ushortx8*)(dst + 8) = *(ushortx8*)&pk[4];
  } else {
    __align__(16) ushort hi[16], lo[16];
    #pragma unroll
    for (int j = 0; j < 16; ++j) {
      float v = (mat == 0) ? acc[j] * SCALE_ : acc[j];
      ushort h = f2bf(v);
      hi[j] = h;
      lo[j] = f2bf(v - bf2f(h));
    }
    ushort* Hd = (mat == 0) ? Qh : Kh;
    ushort* Ld = (mat == 0) ? Ql : Kl;
    const size_t base = ((size_t)gp << 6) + o0;
    *(ushortx8*)(Hd + base)     = *(const ushortx8*)&hi[0];
    *(ushortx8*)(Hd + base + 8) = *(const ushortx8*)&hi[8];
    *(ushortx8*)(Ld + base)     = *(const ushortx8*)&lo[0];
    *(ushortx8*)(Ld + base + 8) = *(const ushortx8*)&lo[8];
  }
}

// ---------------------------------------------------------------------------
// Kernel 2: flash attention, swapped-operand form (unchanged from R2).
// S^T = mfma(K-frag, Q-frag): lane holds S[q=lane&15][kv=16t+4*lq+r]
//   -> softmax fully per-lane (+2 shfl_xor for the 4-group reduce).
// O^T = mfma(V^T-frag, P^T-frag): P^T B-frag built in-register via shfl
//   + selects (no P LDS round-trip, no second barrier).
// Double-buffered LDS, 1 barrier/iter, async-stage. XCD-swizzled blockIdx.
// ---------------------------------------------------------------------------
__global__ __launch_bounds__(256)
void flash_kernel(const ushort* __restrict__ Qh, const ushort* __restrict__ Ql,
                  const ushort* __restrict__ Kh, const ushort* __restrict__ Kl,
                  const ushort* __restrict__ Vt, float* __restrict__ out)
{
  __shared__ __align__(16) ushort KhL[2][64][72];
  __shared__ __align__(16) ushort KlL[2][64][72];
  __shared__ __align__(16) ushort VtL[2][64][72];

  const int tid  = threadIdx.x;
  const int lane = tid & 63;
  const int w    = tid >> 6;
  const int lr   = lane & 15;
  const int lq   = lane >> 4;
  const int koff = lq << 3;

  const int bidx = (blockIdx.x & 7) * 64 + (blockIdx.x >> 3);
  const int b  = bidx >> 6;
  const int qw = ((bidx & 63) << 6) + (w << 4);

  const ushort* KhB = Kh + ((size_t)b << 18);
  const ushort* KlB = Kl + ((size_t)b << 18);
  const ushort* VtB = Vt + ((size_t)b << 18);

  bf16x8 qh[2], ql[2];
  {
    const ushort* qp = Qh + ((((size_t)b << 12) + qw + lr) << 6);
    const ushort* lp = Ql + ((((size_t)b << 12) + qw + lr) << 6);
    qh[0] = *(const bf16x8*)(qp + koff);
    qh[1] = *(const bf16x8*)(qp + 32 + koff);
    ql[0] = *(const bf16x8*)(lp + koff);
    ql[1] = *(const bf16x8*)(lp + 32 + koff);
  }

  const int s0r = tid >> 3, sg = (tid & 7) << 3;
  const int s1r = s0r + 32;

  ushortx8 rkh0, rkh1, rkl0, rkl1, rv0, rv1;
  #define STAGE_LOAD(c0) do { \
    rkh0 = *(const ushortx8*)(KhB + (((size_t)((c0) + s0r)) << 6) + sg); \
    rkh1 = *(const ushortx8*)(KhB + (((size_t)((c0) + s1r)) << 6) + sg); \
    rkl0 = *(const ushortx8*)(KlB + (((size_t)((c0) + s0r)) << 6) + sg); \
    rkl1 = *(const ushortx8*)(KlB + (((size_t)((c0) + s1r)) << 6) + sg); \
    rv0  = *(const ushortx8*)(VtB + ((size_t)s0r << 12) + (c0) + sg); \
    rv1  = *(const ushortx8*)(VtB + ((size_t)s1r << 12) + (c0) + sg); \
  } while (0)
  #define STAGE_WRITE(bf) do { \
    *(ushortx8*)&KhL[bf][s0r][sg] = rkh0; \
    *(ushortx8*)&KhL[bf][s1r][sg] = rkh1; \
    *(ushortx8*)&KlL[bf][s0r][sg] = rkl0; \
    *(ushortx8*)&KlL[bf][s1r][sg] = rkl1; \
    *(ushortx8*)&VtL[bf][s0r][sg] = rv0; \
    *(ushortx8*)&VtL[bf][s1r][sg] = rv1; \
  } while (0)

  STAGE_LOAD(0);
  STAGE_WRITE(0);

  f32x4 acc[4];
  #pragma unroll
  for (int t = 0; t < 4; ++t) acc[t] = (f32x4){0.f, 0.f, 0.f, 0.f};
  float m_run = -INFINITY, l_run = 0.f;
  int cur = 0;

  const int src0 = lr + ((lane & 16) << 1);
  const int src1 = src0 + 16;
  const bool hi2 = (lq & 2) != 0;

  for (int kc = 0; kc < 64; ++kc) {
    __syncthreads();
    STAGE_LOAD(((kc + 1) & 63) << 6);

    f32x4 s[4];
    #pragma unroll
    for (int t = 0; t < 4; ++t) {
      const int row = (t << 4) + lr;
      bf16x8 kh0 = *(const bf16x8*)&KhL[cur][row][koff];
      bf16x8 kh1 = *(const bf16x8*)&KhL[cur][row][32 + koff];
      bf16x8 kl0 = *(const bf16x8*)&KlL[cur][row][koff];
      bf16x8 kl1 = *(const bf16x8*)&KlL[cur][row][32 + koff];
      f32x4 a = (f32x4){0.f, 0.f, 0.f, 0.f};
      a = __builtin_amdgcn_mfma_f32_16x16x32_bf16(kh0, qh[0], a, 0, 0, 0);
      a = __builtin_amdgcn_mfma_f32_16x16x32_bf16(kh1, qh[1], a, 0, 0, 0);
      a = __builtin_amdgcn_mfma_f32_16x16x32_bf16(kl0, qh[0], a, 0, 0, 0);
      a = __builtin_amdgcn_mfma_f32_16x16x32_bf16(kl1, qh[1], a, 0, 0, 0);
      a = __builtin_amdgcn_mfma_f32_16x16x32_bf16(kh0, ql[0], a, 0, 0, 0);
      a = __builtin_amdgcn_mfma_f32_16x16x32_bf16(kh1, ql[1], a, 0, 0, 0);
      s[t] = a;
    }

    float mx = s[0][0];
    #pragma unroll
    for (int t = 0; t < 4; ++t)
      #pragma unroll
      for (int r = 0; r < 4; ++r) mx = fmaxf(mx, s[t][r]);
    mx = fmaxf(mx, __shfl_xor(mx, 16));
    mx = fmaxf(mx, __shfl_xor(mx, 32));
    const float mnew = fmaxf(m_run, mx);
    const float corr = __expf(m_run - mnew);
    float rs = 0.f;
    #pragma unroll
    for (int t = 0; t < 4; ++t) {
      #pragma unroll
      for (int r = 0; r < 4; ++r) {
        float p = __expf(s[t][r] - mnew);
        s[t][r] = p;
        rs += p;
      }
    }
    rs += __shfl_xor(rs, 16);
    rs += __shfl_xor(rs, 32);
    l_run = l_run * corr + rs;
    m_run = mnew;
    #pragma unroll
    for (int t = 0; t < 4; ++t) acc[t] *= corr;

    uint P32[4][2];
    #pragma unroll
    for (int t = 0; t < 4; ++t) {
      P32[t][0] = (uint)f2bf(s[t][0]) | ((uint)f2bf(s[t][1]) << 16);
      P32[t][1] = (uint)f2bf(s[t][2]) | ((uint)f2bf(s[t][3]) << 16);
    }

    #pragma unroll
    for (int mc = 0; mc < 2; ++mc) {
      const int t0 = mc << 1, t1 = t0 + 1;
      uint a00 = (uint)__shfl((int)P32[t0][0], src0);
      uint a10 = (uint)__shfl((int)P32[t1][0], src0);
      uint a01 = (uint)__shfl((int)P32[t0][1], src0);
      uint a11 = (uint)__shfl((int)P32[t1][1], src0);
      uint a02 = (uint)__shfl((int)P32[t0][0], src1);
      uint a12 = (uint)__shfl((int)P32[t1][0], src1);
      uint a03 = (uint)__shfl((int)P32[t0][1], src1);
      uint a13 = (uint)__shfl((int)P32[t1][1], src1);
      union { uint u[4]; bf16x8 v; } pa;
      pa.u[0] = hi2 ? a10 : a00;
      pa.u[1] = hi2 ? a11 : a01;
      pa.u[2] = hi2 ? a12 : a02;
      pa.u[3] = hi2 ? a13 : a03;
      #pragma unroll
      for (int t = 0; t < 4; ++t) {
        bf16x8 vf = *(const bf16x8*)&VtL[cur][(t << 4) + lr][(mc << 5) + koff];
        acc[t] = __builtin_amdgcn_mfma_f32_16x16x32_bf16(vf, pa.v, acc[t], 0, 0, 0);
      }
    }

    STAGE_WRITE(cur ^ 1);
    cur ^= 1;
  }

  const float inv_l = 1.0f / l_run;
  const size_t rowb = ((((size_t)b << 12) + qw + lr) << 6);
  #pragma unroll
  for (int t = 0; t < 4; ++t) {
    f32x4 o4 = acc[t] * inv_l;
    *(f32x4*)(out + rowb + (t << 4) + (lq << 2)) = o4;
  }
  #undef STAGE_LOAD
  #undef STAGE_WRITE
}

extern "C" void kernel_launch(void* const* d_in, const int* in_sizes, int n_in,
                              void* d_out, int out_size, void* d_ws, size_t ws_size,
                              hipStream_t stream) {
  (void)in_sizes; (void)n_in; (void)out_size; (void)ws_size;
  const float* x  = (const float*)d_in[0];
  const float* Wq = (const float*)d_in[1];
  const float* bq = (const float*)d_in[2];
  const float* Wk = (const float*)d_in[3];
  const float* bk = (const float*)d_in[4];
  const float* Wv = (const float*)d_in[5];
  const float* bv = (const float*)d_in[6];
  float* out = (float*)d_out;

  const size_t SZ = (size_t)B_ * N_ * 64;
  ushort* Qh = (ushort*)d_ws;
  ushort* Ql = Qh + SZ;
  ushort* Kh = Ql + SZ;
  ushort* Kl = Kh + SZ;
  ushort* Vt = Kl + SZ;

  proj_kernel<<<dim3(128, 12), dim3(256), 0, stream>>>(x, Wq, bq, Wk, bk, Wv, bv,
                                                       Qh, Ql, Kh, Kl, Vt);
  flash_kernel<<<dim3(B_ * (N_ / 64)), dim3(256), 0, stream>>>(Qh, Ql, Kh, Kl, Vt, out);
}